// Round 2
// baseline (1169.349 us; speedup 1.0000x reference)
//
#include <hip/hip_runtime.h>
#include <stdint.h>

// LPDNet forward on gfx950.
// Layout decisions:
//   hb16/hlo16 : (B,N,64) bf16 hi/lo split of h -> MFMA knn + pure-copy gather
//   featb : (B,N,512) bf16 rows -> [x1 | x2 | x3]; feeds conv3 GEMM and x2 gather
//   idx1/idx2 : (B,N,20) int32
// Graph-conv trick: W·[nbr-ctr | ctr] == W'·[nbr | ctr] with W' = [Wn | Wc-Wn]
// (transformed once in cvt_weights) -> gather staging is pure short8 copies.
// knn64: inner products via 4-term split-bf16 MFMA (hi/lo), residual ~1e-8.
// bf16 conv path (fp32 accum); tolerance is 2% of max|ref|.
// R6: 2-way candidate split (occupancy 22->36%) -> VALUBusy 75%: selection is
// VALU-issue-bound.
// R7: cut selection VALU. (a) score = acc - 0.5*xxM (drop xxR: per-row affine
// shift preserves top-k and the cross-half merge). (b) gate = max of the 4
// sub-threads' minvals via shfl_xor (safe: row_20th >= every local minval),
// replacing racy LDS tau -- tighter pruning, fewer rounds/insertions.
// (c) vmax prefilter (v_max3 tree) skips mask build in the common case.

#define NB 8
#define NP 4096
#define NPTS (NB*NP)

typedef float  floatx4 __attribute__((ext_vector_type(4)));
typedef short  short8  __attribute__((ext_vector_type(8)));

__device__ __forceinline__ unsigned short f2bf(float f) {
  union { float f; uint32_t u; } v; v.f = f;
  uint32_t r = v.u + 0x7fffu + ((v.u >> 16) & 1u);   // RNE
  return (unsigned short)(r >> 16);
}
__device__ __forceinline__ float bf2f(unsigned short h) {
  union { uint32_t u; float f; } v; v.u = ((uint32_t)h) << 16;
  return v.f;
}

__device__ __forceinline__ floatx4 mfma_bf16(short8 a, short8 b, floatx4 c) {
  return __builtin_amdgcn_mfma_f32_16x16x32_bf16(a, b, c, 0, 0, 0);
}

// ---------------- K0: weight conversion + graph-fold transform ---------------
__global__ void cvt_weights(const float* wdg1, unsigned short* wdg1b,
                            const float* wdg2, unsigned short* wdg2b,
                            const float* wsn1, unsigned short* wsn1b,
                            const float* w3, unsigned short* w3b) {
  int i = blockIdx.x * 256 + threadIdx.x;
  if (i < 16384) {                       // wdg1' = [Wn | Wc-Wn], C=64
    int c = i & 127;
    wdg1b[i] = f2bf(wdg1[i] - (c >= 64 ? wdg1[i - 64] : 0.f));
  }
  if (i < 16384) wdg2b[i] = f2bf(wdg2[i]);
  if (i < 65536) {                       // wsn1' = [Wn | Wc-Wn], C=128
    int c = i & 255;
    wsn1b[i] = f2bf(wsn1[i] - (c >= 128 ? wsn1[i - 128] : 0.f));
  }
  if (i < 524288) w3b[i] = f2bf(w3[i]);
}

// ---------------- K1: conv1+relu, conv2+relu -> h hi/lo bf16, xx sums --------
__global__ __launch_bounds__(256) void conv12(
    const float* __restrict__ xin, const float* __restrict__ w1,
    const float* __restrict__ b1, const float* __restrict__ w2,
    const float* __restrict__ b2,
    unsigned short* __restrict__ hb16, unsigned short* __restrict__ hlo16,
    float* __restrict__ hh, float* __restrict__ cc) {
  int wave = threadIdx.x >> 6, lane = threadIdx.x & 63;
  int p = blockIdx.x * 4 + wave;                    // grid 8192
  __shared__ float s_h1[4][64];
  const float* xp = xin + p * 3;
  float c0 = xp[0], c1 = xp[1], c2 = xp[2];
  float v = b1[lane] + w1[lane*3+0]*c0 + w1[lane*3+1]*c1 + w1[lane*3+2]*c2;
  s_h1[wave][lane] = fmaxf(v, 0.f);
  __syncthreads();
  float acc = b2[lane];
  const float* wr = w2 + lane * 64;
  #pragma unroll
  for (int c = 0; c < 64; c += 4) {
    floatx4 w4 = *(const floatx4*)(wr + c);
    acc += w4[0]*s_h1[wave][c]   + w4[1]*s_h1[wave][c+1]
         + w4[2]*s_h1[wave][c+2] + w4[3]*s_h1[wave][c+3];
  }
  acc = fmaxf(acc, 0.f);
  unsigned short hi = f2bf(acc);
  hb16[p*64 + lane] = hi;
  hlo16[p*64 + lane] = f2bf(acc - bf2f(hi));
  float sq = acc * acc;
  #pragma unroll
  for (int off = 32; off; off >>= 1) sq += __shfl_xor(sq, off, 64);
  if (lane == 0) { hh[p] = sq; cc[p] = c0*c0 + c1*c1 + c2*c2; }
}

// ---------------- K2a: knn C=64 via split-bf16 MFMA + ballot top-20 ----------
// 64 rows/block; blockIdx.z selects half of the candidate range (2048 pts).
// score = inner - 0.5*xxM (row-affine-equivalent to full distance; halves
// score-write VALU). Gate = max over the row's 4 sub-threads' minvals
// (register tau via shfl_xor). vmax prefilter skips mask build when nothing
// can pass. Emits sorted (val,idx) top-20 per (row,half) for merge40.
__global__ __launch_bounds__(256) void knn64_mfma(
    const unsigned short* __restrict__ Hhi, const unsigned short* __restrict__ Hlo,
    const float* __restrict__ XX, float* __restrict__ val_out,
    int* __restrict__ idxp_out) {
  __shared__ unsigned short mhi[64][72];   // stride 72: 16B-aligned rows
  __shared__ unsigned short mlo[64][72];
  __shared__ float dots[64][68];
  __shared__ float xxMh[64];
  int b = blockIdx.y;
  int r0 = blockIdx.x * 64;
  int half = blockIdx.z;                   // candidate range half
  int t = threadIdx.x;
  int lane = t & 63, wave = t >> 6;
  int quad = lane >> 4, l15 = lane & 15;
  const unsigned short* Hhib = Hhi + (size_t)b * NP * 64;
  const unsigned short* Hlob = Hlo + (size_t)b * NP * 64;
  short8 ahi[2], alo[2];
  {
    const unsigned short* pr = Hhib + (size_t)(r0 + wave * 16 + l15) * 64 + quad * 8;
    const unsigned short* pl = Hlob + (size_t)(r0 + wave * 16 + l15) * 64 + quad * 8;
    ahi[0] = *(const short8*)pr; ahi[1] = *(const short8*)(pr + 32);
    alo[0] = *(const short8*)pl; alo[1] = *(const short8*)(pl + 32);
  }

  float lv[20]; int li[20];
  #pragma unroll
  for (int s = 0; s < 20; s++) { lv[s] = -__builtin_inff(); li[s] = 0x7fffffff; }
  float minval = -__builtin_inff(); int minpos = 0;
  float tau_reg = -__builtin_inff();
  int row = t >> 2, sub = t & 3;

  int mt0 = half * (NP / 128);             // 32 tiles per half
  for (int mt = mt0; mt < mt0 + NP / 128; mt++) {
    int m0 = mt * 64;
    {                                      // stage m-tile hi/lo (pure copies)
      int pt = t >> 2, c0 = (t & 3) * 16;
      const unsigned short* sh = Hhib + (size_t)(m0 + pt) * 64 + c0;
      const unsigned short* sl = Hlob + (size_t)(m0 + pt) * 64 + c0;
      *(short8*)&mhi[pt][c0]     = *(const short8*)sh;
      *(short8*)&mhi[pt][c0 + 8] = *(const short8*)(sh + 8);
      *(short8*)&mlo[pt][c0]     = *(const short8*)sl;
      *(short8*)&mlo[pt][c0 + 8] = *(const short8*)(sl + 8);
    }
    if (t < 64) xxMh[t] = 0.5f * XX[b * NP + m0 + t];
    __syncthreads();                       // staging visible; prev select done
    #pragma unroll
    for (int nt = 0; nt < 4; nt++) {
      floatx4 acc = (floatx4)0.f;
      #pragma unroll
      for (int ks = 0; ks < 2; ks++) {
        int k0 = ks * 32 + quad * 8;
        short8 bhi = *(short8*)&mhi[nt * 16 + l15][k0];
        short8 blo = *(short8*)&mlo[nt * 16 + l15][k0];
        acc = mfma_bf16(ahi[ks], bhi, acc);
        acc = mfma_bf16(ahi[ks], blo, acc);
        acc = mfma_bf16(alo[ks], bhi, acc);
        acc = mfma_bf16(alo[ks], blo, acc);
      }
      int colg = nt * 16 + l15;
      float xm = xxMh[colg];
      #pragma unroll
      for (int r = 0; r < 4; r++) {
        int mr = wave * 16 + quad * 4 + r;
        dots[mr][colg] = acc[r] - xm;
      }
    }
    __syncthreads();                       // dots ready
    // ---- ballot selection (vmax-prefiltered) ----
    float gate = fmaxf(minval, tau_reg);
    floatx4 dv0 = *(floatx4*)&dots[row][sub * 16];
    floatx4 dv1 = *(floatx4*)&dots[row][sub * 16 + 4];
    floatx4 dv2 = *(floatx4*)&dots[row][sub * 16 + 8];
    floatx4 dv3 = *(floatx4*)&dots[row][sub * 16 + 12];
    float mx0 = fmaxf(fmaxf(dv0[0], dv0[1]), fmaxf(dv0[2], dv0[3]));
    float mx1 = fmaxf(fmaxf(dv1[0], dv1[1]), fmaxf(dv1[2], dv1[3]));
    float mx2 = fmaxf(fmaxf(dv2[0], dv2[1]), fmaxf(dv2[2], dv2[3]));
    float mx3 = fmaxf(fmaxf(dv3[0], dv3[1]), fmaxf(dv3[2], dv3[3]));
    float vmax = fmaxf(fmaxf(mx0, mx1), fmaxf(mx2, mx3));
    uint32_t mask = 0;
    if (vmax > gate) {
      #pragma unroll
      for (int j = 0; j < 4; j++) {
        if (dv0[j] > gate) mask |= 1u << j;
        if (dv1[j] > gate) mask |= 1u << (4 + j);
        if (dv2[j] > gate) mask |= 1u << (8 + j);
        if (dv3[j] > gate) mask |= 1u << (12 + j);
      }
    }
    #pragma clang loop unroll(disable)
    for (int round = 0; round < 16; round++) {
      if (!__any(mask != 0)) break;
      if (mask) {
        int i = __builtin_ctz(mask); mask &= mask - 1;
        float v = dots[row][sub * 16 + i];
        if (v > minval) {
          int gi = m0 + sub * 16 + i;
          #pragma unroll
          for (int s = 0; s < 20; s++)
            if (s == minpos) { lv[s] = v; li[s] = gi; }
          minval = __builtin_inff();
          #pragma unroll
          for (int s = 0; s < 20; s++)
            if (lv[s] < minval) { minval = lv[s]; minpos = s; }
        }
      }
    }
    // row-consensus gate: max over the 4 sub-threads' local 20th-best
    float g = minval;
    g = fmaxf(g, __shfl_xor(g, 1, 64));
    g = fmaxf(g, __shfl_xor(g, 2, 64));
    tau_reg = g;
  }
  int base = ((b * NP + r0 + row) * 2 + half) * 20;
  for (int sel = 0; sel < 20; sel++) {
    float mybv = -__builtin_inff(); int mybi = 0x7fffffff, mybs = 0;
    #pragma unroll
    for (int s = 0; s < 20; s++) {
      bool better = lv[s] > mybv || (lv[s] == mybv && li[s] < mybi);
      if (better) { mybv = lv[s]; mybi = li[s]; mybs = s; }
    }
    float bv = mybv; int bi = mybi;
    float ov = __shfl_xor(bv, 1, 64); int oi = __shfl_xor(bi, 1, 64);
    if (ov > bv || (ov == bv && oi < bi)) { bv = ov; bi = oi; }
    ov = __shfl_xor(bv, 2, 64); oi = __shfl_xor(bi, 2, 64);
    if (ov > bv || (ov == bv && oi < bi)) { bv = ov; bi = oi; }
    if (sub == 0) { val_out[base + sel] = bv; idxp_out[base + sel] = bi; }
    if (bi == mybi) {
      #pragma unroll
      for (int s = 0; s < 20; s++)
        if (s == mybs) { lv[s] = -__builtin_inff(); li[s] = 0x7fffffff; }
    }
  }
}

// ---------------- K2b: knn C=3 (fp32 vector path) ----------------------------
// Same 2-way candidate split + R7 selection (score shift, reg-tau, prefilter).
template<int C>
__global__ __launch_bounds__(256) void knn_topk(
    const float* __restrict__ X, const float* __restrict__ XX,
    float* __restrict__ val_out, int* __restrict__ idxp_out) {
  __shared__ float rowsT[C][68];
  __shared__ float mT[C][68];
  __shared__ float dots[64][68];
  __shared__ float xxMh[64];
  int b = blockIdx.y;
  int r0 = blockIdx.x * 64;
  int half = blockIdx.z;
  int t = threadIdx.x;
  const float* Xb = X + (size_t)b * NP * C;
  for (int e = t; e < C * 64; e += 256) {
    int r = e / C, c = e - r * C;
    rowsT[c][r] = Xb[(r0 + r) * C + c];
  }

  float lv[20]; int li[20];
  #pragma unroll
  for (int s = 0; s < 20; s++) { lv[s] = -__builtin_inff(); li[s] = 0x7fffffff; }
  float minval = -__builtin_inff(); int minpos = 0;
  float tau_reg = -__builtin_inff();

  int tm = t & 15, tr = t >> 4;
  int row = t >> 2, sub = t & 3;

  int mt0 = half * (NP / 128);
  for (int mt = mt0; mt < mt0 + NP / 128; mt++) {
    int m0 = mt * 64;
    for (int e = t; e < C * 64; e += 256) {
      int r = e / C, c = e - r * C;
      mT[c][r] = Xb[(m0 + r) * C + c];
    }
    if (t < 64) xxMh[t] = 0.5f * XX[b * NP + m0 + t];
    __syncthreads();
    float acc[4][4];
    #pragma unroll
    for (int i = 0; i < 4; i++)
      #pragma unroll
      for (int j = 0; j < 4; j++) acc[i][j] = 0.f;
    for (int c = 0; c < C; c++) {
      floatx4 av = *(floatx4*)&rowsT[c][tr * 4];
      floatx4 bv = *(floatx4*)&mT[c][tm * 4];
      #pragma unroll
      for (int i = 0; i < 4; i++)
        #pragma unroll
        for (int j = 0; j < 4; j++) acc[i][j] += av[i] * bv[j];
    }
    #pragma unroll
    for (int i = 0; i < 4; i++) {
      floatx4 sv;
      #pragma unroll
      for (int j = 0; j < 4; j++)
        sv[j] = acc[i][j] - xxMh[tm*4 + j];
      *(floatx4*)&dots[tr*4 + i][tm*4] = sv;
    }
    __syncthreads();
    float gate = fmaxf(minval, tau_reg);
    floatx4 dv0 = *(floatx4*)&dots[row][sub * 16];
    floatx4 dv1 = *(floatx4*)&dots[row][sub * 16 + 4];
    floatx4 dv2 = *(floatx4*)&dots[row][sub * 16 + 8];
    floatx4 dv3 = *(floatx4*)&dots[row][sub * 16 + 12];
    float mx0 = fmaxf(fmaxf(dv0[0], dv0[1]), fmaxf(dv0[2], dv0[3]));
    float mx1 = fmaxf(fmaxf(dv1[0], dv1[1]), fmaxf(dv1[2], dv1[3]));
    float mx2 = fmaxf(fmaxf(dv2[0], dv2[1]), fmaxf(dv2[2], dv2[3]));
    float mx3 = fmaxf(fmaxf(dv3[0], dv3[1]), fmaxf(dv3[2], dv3[3]));
    float vmax = fmaxf(fmaxf(mx0, mx1), fmaxf(mx2, mx3));
    uint32_t mask = 0;
    if (vmax > gate) {
      #pragma unroll
      for (int j = 0; j < 4; j++) {
        if (dv0[j] > gate) mask |= 1u << j;
        if (dv1[j] > gate) mask |= 1u << (4 + j);
        if (dv2[j] > gate) mask |= 1u << (8 + j);
        if (dv3[j] > gate) mask |= 1u << (12 + j);
      }
    }
    #pragma clang loop unroll(disable)
    for (int round = 0; round < 16; round++) {
      if (!__any(mask != 0)) break;
      if (mask) {
        int i = __builtin_ctz(mask); mask &= mask - 1;
        float v = dots[row][sub * 16 + i];
        if (v > minval) {
          int gi = m0 + sub * 16 + i;
          #pragma unroll
          for (int s = 0; s < 20; s++)
            if (s == minpos) { lv[s] = v; li[s] = gi; }
          minval = __builtin_inff();
          #pragma unroll
          for (int s = 0; s < 20; s++)
            if (lv[s] < minval) { minval = lv[s]; minpos = s; }
        }
      }
    }
    float g = minval;
    g = fmaxf(g, __shfl_xor(g, 1, 64));
    g = fmaxf(g, __shfl_xor(g, 2, 64));
    tau_reg = g;
  }
  int base = ((b * NP + r0 + row) * 2 + half) * 20;
  for (int sel = 0; sel < 20; sel++) {
    float mybv = -__builtin_inff(); int mybi = 0x7fffffff, mybs = 0;
    #pragma unroll
    for (int s = 0; s < 20; s++) {
      bool better = lv[s] > mybv || (lv[s] == mybv && li[s] < mybi);
      if (better) { mybv = lv[s]; mybi = li[s]; mybs = s; }
    }
    float bv = mybv; int bi = mybi;
    float ov = __shfl_xor(bv, 1, 64); int oi = __shfl_xor(bi, 1, 64);
    if (ov > bv || (ov == bv && oi < bi)) { bv = ov; bi = oi; }
    ov = __shfl_xor(bv, 2, 64); oi = __shfl_xor(bi, 2, 64);
    if (ov > bv || (ov == bv && oi < bi)) { bv = ov; bi = oi; }
    if (sub == 0) { val_out[base + sel] = bv; idxp_out[base + sel] = bi; }
    if (bi == mybi) {
      #pragma unroll
      for (int s = 0; s < 20; s++)
        if (s == mybs) { lv[s] = -__builtin_inff(); li[s] = 0x7fffffff; }
    }
  }
}

// ---------------- K2c: merge two sorted top-20 halves -> top-20 idx ----------
// Lists are sorted by (value desc, index asc); 2-pointer merge is exact.
__global__ __launch_bounds__(256) void merge40(
    const float* __restrict__ val, const int* __restrict__ midx,
    int* __restrict__ idx_out) {
  int r = blockIdx.x * 256 + threadIdx.x;   // 32768 rows
  const float* vA = val + (size_t)r * 40;
  const int*   iA = midx + (size_t)r * 40;
  int a = 0, bp = 20;
  int base = r * 20;
  #pragma unroll
  for (int s = 0; s < 20; s++) {            // a<=19, bp<=39 at read time
    float va = vA[a], vb = vA[bp];
    int ia = iA[a], ib = iA[bp];
    bool takeA = (va > vb) || (va == vb && ia < ib);
    idx_out[base + s] = takeA ? ia : ib;
    if (takeA) a++; else bp++;
  }
}

// ---------------- K3: dg stage, 4 points/block, M=80 (zero padding) ----------
__global__ __launch_bounds__(256) void dg_stage(
    const unsigned short* __restrict__ hb16, const int* __restrict__ idx1,
    const unsigned short* __restrict__ w1b, const float* __restrict__ bia1,
    const unsigned short* __restrict__ w2b, const float* __restrict__ bia2,
    unsigned short* __restrict__ featb) {
  __shared__ unsigned short s_a[80][136];   // row stride 272 B (16B-aligned)
  __shared__ unsigned short s_v[80][136];
  __shared__ int s_nbf[80];
  int p0 = blockIdx.x * 4;                  // grid 8192; 4 pts share batch b
  int b = p0 >> 12, n0 = p0 & 4095;
  int t = threadIdx.x;
  int lane = t & 63, wave = t >> 6;
  if (t < 80) s_nbf[t] = idx1[p0 * 20 + t];
  __syncthreads();
  const unsigned short* hbb = hb16 + (size_t)b * NP * 64;
  {
    int cc = (t & 15) * 8;                  // uniform per-thread across iters
    int r00 = t >> 4;
    #pragma unroll
    for (int it = 0; it < 5; it++) {
      int row = r00 + it * 16;
      const unsigned short* src = (cc < 64)
        ? hbb + (size_t)s_nbf[row] * 64 + cc
        : hbb + (size_t)(n0 + row / 20) * 64 + (cc - 64);
      *(short8*)&s_a[row][cc] = *(const short8*)src;
    }
  }
  __syncthreads();
  int quad = lane >> 4, mrow = lane & 15;
  int nblock = wave * 32;
  // ---- dg1: A=s_a(80x128), W=w1b' ----
  {
    floatx4 acc[5][2];
    #pragma unroll
    for (int mt = 0; mt < 5; mt++) { acc[mt][0] = (floatx4)0.f; acc[mt][1] = (floatx4)0.f; }
    #pragma unroll
    for (int ks = 0; ks < 4; ks++) {
      int k0 = ks * 32 + quad * 8;
      short8 w0 = *(const short8*)(w1b + (nblock + mrow) * 128 + k0);
      short8 w1v = *(const short8*)(w1b + (nblock + 16 + mrow) * 128 + k0);
      #pragma unroll
      for (int mt = 0; mt < 5; mt++) {
        short8 a = *(short8*)&s_a[mt * 16 + mrow][k0];
        acc[mt][0] = mfma_bf16(a, w0, acc[mt][0]);
        acc[mt][1] = mfma_bf16(a, w1v, acc[mt][1]);
      }
    }
    #pragma unroll
    for (int ns = 0; ns < 2; ns++) {
      int o = nblock + ns * 16 + mrow;
      float bz = bia1[o];
      #pragma unroll
      for (int mt = 0; mt < 5; mt++)
        #pragma unroll
        for (int r = 0; r < 4; r++)
          s_v[mt * 16 + quad * 4 + r][o] = f2bf(fmaxf(acc[mt][ns][r] + bz, 0.f));
    }
  }
  __syncthreads();                          // s_v ready; all s_a reads done
  #pragma unroll
  for (int it = 0; it < 2; it++) {
    int e = t + it * 256;                   // 512 outputs
    int pt = e >> 7, o = e & 127;
    float mx = 0.f;
    for (int k = 0; k < 20; k++) mx = fmaxf(mx, bf2f(s_v[pt * 20 + k][o]));
    featb[(size_t)(p0 + pt) * 512 + o] = f2bf(mx);
  }
  // ---- dg2: A=s_v(80x128), W=w2b, relu -> s_a (reuse) ----
  {
    floatx4 acc[5][2];
    #pragma unroll
    for (int mt = 0; mt < 5; mt++) { acc[mt][0] = (floatx4)0.f; acc[mt][1] = (floatx4)0.f; }
    #pragma unroll
    for (int ks = 0; ks < 4; ks++) {
      int k0 = ks * 32 + quad * 8;
      short8 w0 = *(const short8*)(w2b + (nblock + mrow) * 128 + k0);
      short8 w1v = *(const short8*)(w2b + (nblock + 16 + mrow) * 128 + k0);
      #pragma unroll
      for (int mt = 0; mt < 5; mt++) {
        short8 a = *(short8*)&s_v[mt * 16 + mrow][k0];
        acc[mt][0] = mfma_bf16(a, w0, acc[mt][0]);
        acc[mt][1] = mfma_bf16(a, w1v, acc[mt][1]);
      }
    }
    #pragma unroll
    for (int ns = 0; ns < 2; ns++) {
      int o = nblock + ns * 16 + mrow;
      float bz = bia2[o];
      #pragma unroll
      for (int mt = 0; mt < 5; mt++)
        #pragma unroll
        for (int r = 0; r < 4; r++)
          s_a[mt * 16 + quad * 4 + r][o] = f2bf(fmaxf(acc[mt][ns][r] + bz, 0.f));
    }
  }
  __syncthreads();
  #pragma unroll
  for (int it = 0; it < 2; it++) {
    int e = t + it * 256;
    int pt = e >> 7, o = e & 127;
    float mx = 0.f;
    for (int k = 0; k < 20; k++) mx = fmaxf(mx, bf2f(s_a[pt * 20 + k][o]));
    featb[(size_t)(p0 + pt) * 512 + 128 + o] = f2bf(mx);
  }
}

// ---------------- K4: sn stage, 4 points/block, M=80 -------------------------
__global__ __launch_bounds__(256) void sn_stage(
    const int* __restrict__ idx2, const unsigned short* __restrict__ wb,
    const float* __restrict__ bias, unsigned short* __restrict__ featb) {
  __shared__ unsigned short s_a[80][264];   // row stride 528 B (16B-aligned)
  __shared__ int s_nbf[80];
  int p0 = blockIdx.x * 4;
  int b = p0 >> 12, n0 = p0 & 4095;
  int bb = b << 12;
  int t = threadIdx.x;
  int lane = t & 63, wave = t >> 6;
  if (t < 80) s_nbf[t] = idx2[p0 * 20 + t];
  __syncthreads();
  {
    int cc = (t & 31) * 8;                  // uniform per-thread
    int r00 = t >> 5;
    #pragma unroll
    for (int it = 0; it < 10; it++) {
      int row = r00 + it * 8;
      const unsigned short* src = (cc < 128)
        ? featb + (size_t)(bb + s_nbf[row]) * 512 + 128 + cc
        : featb + (size_t)(bb + n0 + row / 20) * 512 + cc;   // 128+(cc-128)
      *(short8*)&s_a[row][cc] = *(const short8*)src;
    }
  }
  __syncthreads();
  int quad = lane >> 4, mrow = lane & 15;
  int nblock = wave * 64;
  floatx4 acc[5][4];
  #pragma unroll
  for (int mt = 0; mt < 5; mt++)
    #pragma unroll
    for (int ns = 0; ns < 4; ns++) acc[mt][ns] = (floatx4)0.f;
  #pragma unroll
  for (int ks = 0; ks < 8; ks++) {
    int k0 = ks * 32 + quad * 8;
    short8 w[4];
    #pragma unroll
    for (int ns = 0; ns < 4; ns++)
      w[ns] = *(const short8*)(wb + (nblock + ns * 16 + mrow) * 256 + k0);
    #pragma unroll
    for (int mt = 0; mt < 5; mt++) {
      short8 a = *(short8*)&s_a[mt * 16 + mrow][k0];
      #pragma unroll
      for (int ns = 0; ns < 4; ns++)
        acc[mt][ns] = mfma_bf16(a, w[ns], acc[mt][ns]);
    }
  }
  __syncthreads();                          // all s_a reads done
  #pragma unroll
  for (int ns = 0; ns < 4; ns++) {
    int o = nblock + ns * 16 + mrow;
    float bz = bias[o];
    #pragma unroll
    for (int mt = 0; mt < 5; mt++)
      #pragma unroll
      for (int r = 0; r < 4; r++)
        s_a[mt * 16 + quad * 4 + r][o] = f2bf(fmaxf(acc[mt][ns][r] + bz, 0.f));
  }
  __syncthreads();
  #pragma unroll
  for (int it = 0; it < 4; it++) {
    int e = t + it * 256;                   // 1024 outputs
    int pt = e >> 8, o = e & 255;
    float mx = 0.f;
    for (int k = 0; k < 20; k++) mx = fmaxf(mx, bf2f(s_a[pt * 20 + k][o]));
    featb[(size_t)(p0 + pt) * 512 + 256 + o] = f2bf(mx);
  }
}

// ---------------- K5: conv3 GEMM ---------------------------------------------
__global__ __launch_bounds__(256) void conv3_gemm(
    const unsigned short* __restrict__ w3b, const unsigned short* __restrict__ featb,
    const float* __restrict__ b3, float* __restrict__ out) {
  __shared__ unsigned short s_a[128][40];
  __shared__ unsigned short s_b[128][40];
  int o0 = blockIdx.x * 128, p0 = blockIdx.y * 128;
  int t = threadIdx.x, lane = t & 63, wave = t >> 6;
  int wy = wave >> 1, wx = wave & 1;
  int quad = lane >> 4, l15 = lane & 15;
  floatx4 acc[4][4];
  #pragma unroll
  for (int i = 0; i < 4; i++)
    #pragma unroll
    for (int j = 0; j < 4; j++) acc[i][j] = (floatx4)0.f;
  for (int kc = 0; kc < 16; kc++) {
    __syncthreads();
    for (int e = t; e < 512; e += 256) {
      int r = e >> 2, c8 = (e & 3) * 8;
      *(short8*)&s_a[r][c8] = *(const short8*)(w3b + (size_t)(o0 + r) * 512 + kc * 32 + c8);
    }
    for (int e = t; e < 512; e += 256) {
      int r = e >> 2, c8 = (e & 3) * 8;
      *(short8*)&s_b[r][c8] = *(const short8*)(featb + (size_t)(p0 + r) * 512 + kc * 32 + c8);
    }
    __syncthreads();
    int k0 = quad * 8;
    short8 af[4], bfr[4];
    #pragma unroll
    for (int i = 0; i < 4; i++) af[i] = *(short8*)&s_a[wy * 64 + i * 16 + l15][k0];
    #pragma unroll
    for (int j = 0; j < 4; j++) bfr[j] = *(short8*)&s_b[wx * 64 + j * 16 + l15][k0];
    #pragma unroll
    for (int i = 0; i < 4; i++)
      #pragma unroll
      for (int j = 0; j < 4; j++) acc[i][j] = mfma_bf16(af[i], bfr[j], acc[i][j]);
  }
  #pragma unroll
  for (int i = 0; i < 4; i++)
    #pragma unroll
    for (int j = 0; j < 4; j++) {
      int pl = p0 + wx * 64 + j * 16 + l15;
      int bI = pl >> 12, n = pl & 4095;
      #pragma unroll
      for (int r = 0; r < 4; r++) {
        int o = o0 + wy * 64 + i * 16 + quad * 4 + r;
        out[(size_t)(bI * 1024 + o) * 4096 + n] = fmaxf(acc[i][j][r] + b3[o], 0.f);
      }
    }
}

// ---------------- launcher ---------------------------------------------------
extern "C" void kernel_launch(void* const* d_in, const int* in_sizes, int n_in,
                              void* d_out, int out_size, void* d_ws, size_t ws_size,
                              hipStream_t stream) {
  const float* x    = (const float*)d_in[0];
  const float* w1   = (const float*)d_in[1];
  const float* b1   = (const float*)d_in[2];
  const float* w2   = (const float*)d_in[3];
  const float* b2   = (const float*)d_in[4];
  const float* wdg1 = (const float*)d_in[5];
  const float* bdg1 = (const float*)d_in[6];
  const float* wdg2 = (const float*)d_in[7];
  const float* bdg2 = (const float*)d_in[8];
  const float* wsn1 = (const float*)d_in[9];
  const float* bsn1 = (const float*)d_in[10];
  const float* w3   = (const float*)d_in[11];
  const float* b3   = (const float*)d_in[12];

  float* ws = (float*)d_ws;                 // offsets in float slots
  unsigned short* hlo16 = (unsigned short*)ws;               // 2,097,152 bf16 (1,048,576 slots)
  float* hh = ws + 2097152;                 //    32,768
  float* cc = ws + 2129920;                 //    32,768
  int* idx1 = (int*)(ws + 2162688);         //   655,360
  int* idx2 = (int*)(ws + 2818048);         //   655,360
  unsigned short* featb = (unsigned short*)(ws + 3473408);   // 16,777,216 bf16
  unsigned short* wdg1b = (unsigned short*)(ws + 11862016);
  unsigned short* wdg2b = (unsigned short*)(ws + 11870208);
  unsigned short* wsn1b = (unsigned short*)(ws + 11878400);
  unsigned short* w3b   = (unsigned short*)(ws + 11911168);
  unsigned short* hb16  = (unsigned short*)(ws + 12173312); // 2,097,152 bf16

  // knn pair scratch aliases the featb region (dead until dg_stage; the
  // merge kernels consume it before dg_stage/sn_stage write featb).
  float* c1val = ws + 3473408;              // 32768*40 = 1,310,720 slots
  int*   c1idx = (int*)(ws + 4784128);      // 1,310,720
  float* c2val = ws + 6094848;              // 1,310,720
  int*   c2idx = (int*)(ws + 7405568);      // 1,310,720 (ends 8,716,288 < 11,862,016)

  cvt_weights<<<2048, 256, 0, stream>>>(wdg1, wdg1b, wdg2, wdg2b,
                                        wsn1, wsn1b, w3, w3b);
  conv12<<<8192, 256, 0, stream>>>(x, w1, b1, w2, b2, hb16, hlo16, hh, cc);
  knn64_mfma<<<dim3(64, 8, 2), 256, 0, stream>>>(hb16, hlo16, hh, c1val, c1idx);
  knn_topk<3><<<dim3(64, 8, 2), 256, 0, stream>>>(x, cc, c2val, c2idx);
  merge40<<<128, 256, 0, stream>>>(c1val, c1idx, idx1);
  merge40<<<128, 256, 0, stream>>>(c2val, c2idx, idx2);
  dg_stage<<<8192, 256, 0, stream>>>(hb16, idx1, wdg1b, bdg1, wdg2b, bdg2, featb);
  sn_stage<<<8192, 256, 0, stream>>>(idx2, wsn1b, bsn1, featb);
  conv3_gemm<<<dim3(8, 256), 256, 0, stream>>>(w3b, featb, b3, (float*)d_out);
}

// Round 3
// 1033.215 us; speedup vs baseline: 1.1318x; 1.1318x over previous
//
#include <hip/hip_runtime.h>
#include <stdint.h>

// LPDNet forward on gfx950.
// Layout decisions:
//   hb16/hlo16 : (B,N,64) bf16 hi/lo split of h -> MFMA knn + pure-copy gather
//   featb : (B,N,512) bf16 rows -> [x1 | x2 | x3]; feeds conv3 GEMM and x2 gather
//   idx1/idx2 : (B,N,20) int32
// Graph-conv trick: W·[nbr-ctr | ctr] == W'·[nbr | ctr] with W' = [Wn | Wc-Wn]
// (transformed once in cvt_weights) -> gather staging is pure short8 copies.
// knn64: inner products via 4-term split-bf16 MFMA (hi/lo), residual ~1e-8.
// bf16 conv path (fp32 accum); tolerance is 2% of max|ref|.
// R8: post-mortem of R6/R7 -- candidate split duplicated top-20 warm-up
// (+40% VALU-cycles) and R7's gate/prefilter added serial deps without
// removing work. Reverted to single-pass R5 machinery. New: (1) m-tile
// 64->128 in knn64 (barriers 128->64, 2x staging/MFMA ILP; LDS 37->71KB,
// still 2 blocks/CU since grid=512 caps residency); (2) score = acc-0.5*xxM
// (per-row affine shift preserves top-k + tie-break; drops xxR + 2/3 of
// score-write VALU). Selection/epilogue = R5-proven, 32-bit masks.

#define NB 8
#define NP 4096
#define NPTS (NB*NP)

typedef float  floatx4 __attribute__((ext_vector_type(4)));
typedef short  short8  __attribute__((ext_vector_type(8)));

__device__ __forceinline__ unsigned short f2bf(float f) {
  union { float f; uint32_t u; } v; v.f = f;
  uint32_t r = v.u + 0x7fffu + ((v.u >> 16) & 1u);   // RNE
  return (unsigned short)(r >> 16);
}
__device__ __forceinline__ float bf2f(unsigned short h) {
  union { uint32_t u; float f; } v; v.u = ((uint32_t)h) << 16;
  return v.f;
}

__device__ __forceinline__ floatx4 mfma_bf16(short8 a, short8 b, floatx4 c) {
  return __builtin_amdgcn_mfma_f32_16x16x32_bf16(a, b, c, 0, 0, 0);
}

// ---------------- K0: weight conversion + graph-fold transform ---------------
__global__ void cvt_weights(const float* wdg1, unsigned short* wdg1b,
                            const float* wdg2, unsigned short* wdg2b,
                            const float* wsn1, unsigned short* wsn1b,
                            const float* w3, unsigned short* w3b) {
  int i = blockIdx.x * 256 + threadIdx.x;
  if (i < 16384) {                       // wdg1' = [Wn | Wc-Wn], C=64
    int c = i & 127;
    wdg1b[i] = f2bf(wdg1[i] - (c >= 64 ? wdg1[i - 64] : 0.f));
  }
  if (i < 16384) wdg2b[i] = f2bf(wdg2[i]);
  if (i < 65536) {                       // wsn1' = [Wn | Wc-Wn], C=128
    int c = i & 255;
    wsn1b[i] = f2bf(wsn1[i] - (c >= 128 ? wsn1[i - 128] : 0.f));
  }
  if (i < 524288) w3b[i] = f2bf(w3[i]);
}

// ---------------- K1: conv1+relu, conv2+relu -> h hi/lo bf16, xx sums --------
__global__ __launch_bounds__(256) void conv12(
    const float* __restrict__ xin, const float* __restrict__ w1,
    const float* __restrict__ b1, const float* __restrict__ w2,
    const float* __restrict__ b2,
    unsigned short* __restrict__ hb16, unsigned short* __restrict__ hlo16,
    float* __restrict__ hh, float* __restrict__ cc) {
  int wave = threadIdx.x >> 6, lane = threadIdx.x & 63;
  int p = blockIdx.x * 4 + wave;                    // grid 8192
  __shared__ float s_h1[4][64];
  const float* xp = xin + p * 3;
  float c0 = xp[0], c1 = xp[1], c2 = xp[2];
  float v = b1[lane] + w1[lane*3+0]*c0 + w1[lane*3+1]*c1 + w1[lane*3+2]*c2;
  s_h1[wave][lane] = fmaxf(v, 0.f);
  __syncthreads();
  float acc = b2[lane];
  const float* wr = w2 + lane * 64;
  #pragma unroll
  for (int c = 0; c < 64; c += 4) {
    floatx4 w4 = *(const floatx4*)(wr + c);
    acc += w4[0]*s_h1[wave][c]   + w4[1]*s_h1[wave][c+1]
         + w4[2]*s_h1[wave][c+2] + w4[3]*s_h1[wave][c+3];
  }
  acc = fmaxf(acc, 0.f);
  unsigned short hi = f2bf(acc);
  hb16[p*64 + lane] = hi;
  hlo16[p*64 + lane] = f2bf(acc - bf2f(hi));
  float sq = acc * acc;
  #pragma unroll
  for (int off = 32; off; off >>= 1) sq += __shfl_xor(sq, off, 64);
  if (lane == 0) { hh[p] = sq; cc[p] = c0*c0 + c1*c1 + c2*c2; }
}

// ---------------- K2a: knn C=64 via split-bf16 MFMA + ballot top-20 ----------
// 64 rows/block, single pass over all 4096 candidates in 32 tiles of 128.
// Wave w owns rows 16w..16w+15: A-frags (hi/lo, 2 k-steps) loaded once from
// global. Per m-tile: stage 128 rows hi/lo (pure copies) + 0.5*xxM; 8 n-tiles
// x 2 k-steps x 4 chained MFMAs; score = acc - 0.5*xxM written to dots in C/D
// layout (row=quad*4+reg, col=lane&15). Selection = R5 ballot machinery with
// 32-bit masks (sub covers 32 cols); racy-LDS tau gate (proven).
__global__ __launch_bounds__(256) void knn64_mfma(
    const unsigned short* __restrict__ Hhi, const unsigned short* __restrict__ Hlo,
    const float* __restrict__ XX, int* __restrict__ idx_out) {
  __shared__ unsigned short mhi[128][72];  // stride 72: 16B-aligned rows
  __shared__ unsigned short mlo[128][72];
  __shared__ float dots[64][132];
  __shared__ float xxMh[128];
  __shared__ float tau[64];
  int b = blockIdx.y;
  int r0 = blockIdx.x * 64;
  int t = threadIdx.x;
  int lane = t & 63, wave = t >> 6;
  int quad = lane >> 4, l15 = lane & 15;
  const unsigned short* Hhib = Hhi + (size_t)b * NP * 64;
  const unsigned short* Hlob = Hlo + (size_t)b * NP * 64;
  short8 ahi[2], alo[2];
  {
    const unsigned short* pr = Hhib + (size_t)(r0 + wave * 16 + l15) * 64 + quad * 8;
    const unsigned short* pl = Hlob + (size_t)(r0 + wave * 16 + l15) * 64 + quad * 8;
    ahi[0] = *(const short8*)pr; ahi[1] = *(const short8*)(pr + 32);
    alo[0] = *(const short8*)pl; alo[1] = *(const short8*)(pl + 32);
  }
  if (t < 64) tau[t] = -__builtin_inff();

  float lv[20]; int li[20];
  #pragma unroll
  for (int s = 0; s < 20; s++) { lv[s] = -__builtin_inff(); li[s] = 0x7fffffff; }
  float minval = -__builtin_inff(); int minpos = 0;
  int row = t >> 2, sub = t & 3;

  for (int mt = 0; mt < NP / 128; mt++) {
    int m0 = mt * 128;
    {                                      // stage 128-row m-tile hi/lo
      int hf = t & 1, r = (t >> 1) & 127;  // 2 threads per row, 64B each
      int c0 = hf * 32;
      const unsigned short* sh = Hhib + (size_t)(m0 + r) * 64 + c0;
      const unsigned short* sl = Hlob + (size_t)(m0 + r) * 64 + c0;
      *(short8*)&mhi[r][c0]      = *(const short8*)sh;
      *(short8*)&mhi[r][c0 + 8]  = *(const short8*)(sh + 8);
      *(short8*)&mhi[r][c0 + 16] = *(const short8*)(sh + 16);
      *(short8*)&mhi[r][c0 + 24] = *(const short8*)(sh + 24);
      *(short8*)&mlo[r][c0]      = *(const short8*)sl;
      *(short8*)&mlo[r][c0 + 8]  = *(const short8*)(sl + 8);
      *(short8*)&mlo[r][c0 + 16] = *(const short8*)(sl + 16);
      *(short8*)&mlo[r][c0 + 24] = *(const short8*)(sl + 24);
    }
    if (t < 128) xxMh[t] = 0.5f * XX[b * NP + m0 + t];
    __syncthreads();                       // staging visible; prev select done
    #pragma unroll
    for (int nt = 0; nt < 8; nt++) {
      floatx4 acc = (floatx4)0.f;
      #pragma unroll
      for (int ks = 0; ks < 2; ks++) {
        int k0 = ks * 32 + quad * 8;
        short8 bhi = *(short8*)&mhi[nt * 16 + l15][k0];
        short8 blo = *(short8*)&mlo[nt * 16 + l15][k0];
        acc = mfma_bf16(ahi[ks], bhi, acc);
        acc = mfma_bf16(ahi[ks], blo, acc);
        acc = mfma_bf16(alo[ks], bhi, acc);
        acc = mfma_bf16(alo[ks], blo, acc);
      }
      int colg = nt * 16 + l15;
      float xm = xxMh[colg];
      #pragma unroll
      for (int r = 0; r < 4; r++) {
        int mr = wave * 16 + quad * 4 + r;
        dots[mr][colg] = acc[r] - xm;
      }
    }
    __syncthreads();                       // dots ready
    // ---- R5 ballot selection, 32 cols per sub-thread ----
    float gate = fmaxf(minval, tau[row]);
    floatx4 dv[8];
    #pragma unroll
    for (int q = 0; q < 8; q++) dv[q] = *(floatx4*)&dots[row][sub * 32 + q * 4];
    uint32_t mask = 0;
    #pragma unroll
    for (int q = 0; q < 8; q++)
      #pragma unroll
      for (int j = 0; j < 4; j++)
        if (dv[q][j] > gate) mask |= 1u << (q * 4 + j);
    #pragma clang loop unroll(disable)
    for (int round = 0; round < 32; round++) {
      if (!__any(mask != 0)) break;
      if (mask) {
        int i = __builtin_ctz(mask); mask &= mask - 1;
        float v = dots[row][sub * 32 + i];
        if (v > minval) {
          int gi = m0 + sub * 32 + i;
          #pragma unroll
          for (int s = 0; s < 20; s++)
            if (s == minpos) { lv[s] = v; li[s] = gi; }
          minval = __builtin_inff();
          #pragma unroll
          for (int s = 0; s < 20; s++)
            if (lv[s] < minval) { minval = lv[s]; minpos = s; }
        }
      }
    }
    tau[row] = fmaxf(tau[row], minval);
  }
  int base = (b * NP + r0 + row) * 20;
  for (int sel = 0; sel < 20; sel++) {
    float mybv = -__builtin_inff(); int mybi = 0x7fffffff, mybs = 0;
    #pragma unroll
    for (int s = 0; s < 20; s++) {
      bool better = lv[s] > mybv || (lv[s] == mybv && li[s] < mybi);
      if (better) { mybv = lv[s]; mybi = li[s]; mybs = s; }
    }
    float bv = mybv; int bi = mybi;
    float ov = __shfl_xor(bv, 1, 64); int oi = __shfl_xor(bi, 1, 64);
    if (ov > bv || (ov == bv && oi < bi)) { bv = ov; bi = oi; }
    ov = __shfl_xor(bv, 2, 64); oi = __shfl_xor(bi, 2, 64);
    if (ov > bv || (ov == bv && oi < bi)) { bv = ov; bi = oi; }
    if (sub == 0) idx_out[base + sel] = bi;
    if (bi == mybi) {
      #pragma unroll
      for (int s = 0; s < 20; s++)
        if (s == mybs) { lv[s] = -__builtin_inff(); li[s] = 0x7fffffff; }
    }
  }
}

// ---------------- K2b: knn C=3 (fp32 vector path, R5-proven) -----------------
// R5 structure (64-wide tiles) + score shift (acc - 0.5*xxM, xxR dropped).
template<int C>
__global__ __launch_bounds__(256) void knn_topk(
    const float* __restrict__ X, const float* __restrict__ XX,
    int* __restrict__ idx_out) {
  __shared__ float rowsT[C][68];
  __shared__ float mT[C][68];
  __shared__ float dots[64][68];
  __shared__ float xxMh[64];
  __shared__ float tau[64];
  int b = blockIdx.y;
  int r0 = blockIdx.x * 64;
  int t = threadIdx.x;
  const float* Xb = X + (size_t)b * NP * C;
  for (int e = t; e < C * 64; e += 256) {
    int r = e / C, c = e - r * C;
    rowsT[c][r] = Xb[(r0 + r) * C + c];
  }
  if (t < 64) tau[t] = -__builtin_inff();

  float lv[20]; int li[20];
  #pragma unroll
  for (int s = 0; s < 20; s++) { lv[s] = -__builtin_inff(); li[s] = 0x7fffffff; }
  float minval = -__builtin_inff(); int minpos = 0;

  int tm = t & 15, tr = t >> 4;
  int row = t >> 2, sub = t & 3;

  for (int mt = 0; mt < NP / 64; mt++) {
    int m0 = mt * 64;
    for (int e = t; e < C * 64; e += 256) {
      int r = e / C, c = e - r * C;
      mT[c][r] = Xb[(m0 + r) * C + c];
    }
    if (t < 64) xxMh[t] = 0.5f * XX[b * NP + m0 + t];
    __syncthreads();
    float acc[4][4];
    #pragma unroll
    for (int i = 0; i < 4; i++)
      #pragma unroll
      for (int j = 0; j < 4; j++) acc[i][j] = 0.f;
    for (int c = 0; c < C; c++) {
      floatx4 av = *(floatx4*)&rowsT[c][tr * 4];
      floatx4 bv = *(floatx4*)&mT[c][tm * 4];
      #pragma unroll
      for (int i = 0; i < 4; i++)
        #pragma unroll
        for (int j = 0; j < 4; j++) acc[i][j] += av[i] * bv[j];
    }
    #pragma unroll
    for (int i = 0; i < 4; i++) {
      floatx4 sv;
      #pragma unroll
      for (int j = 0; j < 4; j++)
        sv[j] = acc[i][j] - xxMh[tm*4 + j];
      *(floatx4*)&dots[tr*4 + i][tm*4] = sv;
    }
    __syncthreads();
    float gate = fmaxf(minval, tau[row]);
    floatx4 dv0 = *(floatx4*)&dots[row][sub * 16];
    floatx4 dv1 = *(floatx4*)&dots[row][sub * 16 + 4];
    floatx4 dv2 = *(floatx4*)&dots[row][sub * 16 + 8];
    floatx4 dv3 = *(floatx4*)&dots[row][sub * 16 + 12];
    uint32_t mask = 0;
    #pragma unroll
    for (int j = 0; j < 4; j++) {
      if (dv0[j] > gate) mask |= 1u << j;
      if (dv1[j] > gate) mask |= 1u << (4 + j);
      if (dv2[j] > gate) mask |= 1u << (8 + j);
      if (dv3[j] > gate) mask |= 1u << (12 + j);
    }
    #pragma clang loop unroll(disable)
    for (int round = 0; round < 16; round++) {
      if (!__any(mask != 0)) break;
      if (mask) {
        int i = __builtin_ctz(mask); mask &= mask - 1;
        float v = dots[row][sub * 16 + i];
        if (v > minval) {
          int gi = m0 + sub * 16 + i;
          #pragma unroll
          for (int s = 0; s < 20; s++)
            if (s == minpos) { lv[s] = v; li[s] = gi; }
          minval = __builtin_inff();
          #pragma unroll
          for (int s = 0; s < 20; s++)
            if (lv[s] < minval) { minval = lv[s]; minpos = s; }
        }
      }
    }
    tau[row] = fmaxf(tau[row], minval);
  }
  int base = (b * NP + r0 + row) * 20;
  for (int sel = 0; sel < 20; sel++) {
    float mybv = -__builtin_inff(); int mybi = 0x7fffffff, mybs = 0;
    #pragma unroll
    for (int s = 0; s < 20; s++) {
      bool better = lv[s] > mybv || (lv[s] == mybv && li[s] < mybi);
      if (better) { mybv = lv[s]; mybi = li[s]; mybs = s; }
    }
    float bv = mybv; int bi = mybi;
    float ov = __shfl_xor(bv, 1, 64); int oi = __shfl_xor(bi, 1, 64);
    if (ov > bv || (ov == bv && oi < bi)) { bv = ov; bi = oi; }
    ov = __shfl_xor(bv, 2, 64); oi = __shfl_xor(bi, 2, 64);
    if (ov > bv || (ov == bv && oi < bi)) { bv = ov; bi = oi; }
    if (sub == 0) idx_out[base + sel] = bi;
    if (bi == mybi) {
      #pragma unroll
      for (int s = 0; s < 20; s++)
        if (s == mybs) { lv[s] = -__builtin_inff(); li[s] = 0x7fffffff; }
    }
  }
}

// ---------------- K3: dg stage, 4 points/block, M=80 (zero padding) ----------
__global__ __launch_bounds__(256) void dg_stage(
    const unsigned short* __restrict__ hb16, const int* __restrict__ idx1,
    const unsigned short* __restrict__ w1b, const float* __restrict__ bia1,
    const unsigned short* __restrict__ w2b, const float* __restrict__ bia2,
    unsigned short* __restrict__ featb) {
  __shared__ unsigned short s_a[80][136];   // row stride 272 B (16B-aligned)
  __shared__ unsigned short s_v[80][136];
  __shared__ int s_nbf[80];
  int p0 = blockIdx.x * 4;                  // grid 8192; 4 pts share batch b
  int b = p0 >> 12, n0 = p0 & 4095;
  int t = threadIdx.x;
  int lane = t & 63, wave = t >> 6;
  if (t < 80) s_nbf[t] = idx1[p0 * 20 + t];
  __syncthreads();
  const unsigned short* hbb = hb16 + (size_t)b * NP * 64;
  {
    int cc = (t & 15) * 8;                  // uniform per-thread across iters
    int r00 = t >> 4;
    #pragma unroll
    for (int it = 0; it < 5; it++) {
      int row = r00 + it * 16;
      const unsigned short* src = (cc < 64)
        ? hbb + (size_t)s_nbf[row] * 64 + cc
        : hbb + (size_t)(n0 + row / 20) * 64 + (cc - 64);
      *(short8*)&s_a[row][cc] = *(const short8*)src;
    }
  }
  __syncthreads();
  int quad = lane >> 4, mrow = lane & 15;
  int nblock = wave * 32;
  // ---- dg1: A=s_a(80x128), W=w1b' ----
  {
    floatx4 acc[5][2];
    #pragma unroll
    for (int mt = 0; mt < 5; mt++) { acc[mt][0] = (floatx4)0.f; acc[mt][1] = (floatx4)0.f; }
    #pragma unroll
    for (int ks = 0; ks < 4; ks++) {
      int k0 = ks * 32 + quad * 8;
      short8 w0 = *(const short8*)(w1b + (nblock + mrow) * 128 + k0);
      short8 w1v = *(const short8*)(w1b + (nblock + 16 + mrow) * 128 + k0);
      #pragma unroll
      for (int mt = 0; mt < 5; mt++) {
        short8 a = *(short8*)&s_a[mt * 16 + mrow][k0];
        acc[mt][0] = mfma_bf16(a, w0, acc[mt][0]);
        acc[mt][1] = mfma_bf16(a, w1v, acc[mt][1]);
      }
    }
    #pragma unroll
    for (int ns = 0; ns < 2; ns++) {
      int o = nblock + ns * 16 + mrow;
      float bz = bia1[o];
      #pragma unroll
      for (int mt = 0; mt < 5; mt++)
        #pragma unroll
        for (int r = 0; r < 4; r++)
          s_v[mt * 16 + quad * 4 + r][o] = f2bf(fmaxf(acc[mt][ns][r] + bz, 0.f));
    }
  }
  __syncthreads();                          // s_v ready; all s_a reads done
  #pragma unroll
  for (int it = 0; it < 2; it++) {
    int e = t + it * 256;                   // 512 outputs
    int pt = e >> 7, o = e & 127;
    float mx = 0.f;
    for (int k = 0; k < 20; k++) mx = fmaxf(mx, bf2f(s_v[pt * 20 + k][o]));
    featb[(size_t)(p0 + pt) * 512 + o] = f2bf(mx);
  }
  // ---- dg2: A=s_v(80x128), W=w2b, relu -> s_a (reuse) ----
  {
    floatx4 acc[5][2];
    #pragma unroll
    for (int mt = 0; mt < 5; mt++) { acc[mt][0] = (floatx4)0.f; acc[mt][1] = (floatx4)0.f; }
    #pragma unroll
    for (int ks = 0; ks < 4; ks++) {
      int k0 = ks * 32 + quad * 8;
      short8 w0 = *(const short8*)(w2b + (nblock + mrow) * 128 + k0);
      short8 w1v = *(const short8*)(w2b + (nblock + 16 + mrow) * 128 + k0);
      #pragma unroll
      for (int mt = 0; mt < 5; mt++) {
        short8 a = *(short8*)&s_v[mt * 16 + mrow][k0];
        acc[mt][0] = mfma_bf16(a, w0, acc[mt][0]);
        acc[mt][1] = mfma_bf16(a, w1v, acc[mt][1]);
      }
    }
    #pragma unroll
    for (int ns = 0; ns < 2; ns++) {
      int o = nblock + ns * 16 + mrow;
      float bz = bia2[o];
      #pragma unroll
      for (int mt = 0; mt < 5; mt++)
        #pragma unroll
        for (int r = 0; r < 4; r++)
          s_a[mt * 16 + quad * 4 + r][o] = f2bf(fmaxf(acc[mt][ns][r] + bz, 0.f));
    }
  }
  __syncthreads();
  #pragma unroll
  for (int it = 0; it < 2; it++) {
    int e = t + it * 256;
    int pt = e >> 7, o = e & 127;
    float mx = 0.f;
    for (int k = 0; k < 20; k++) mx = fmaxf(mx, bf2f(s_a[pt * 20 + k][o]));
    featb[(size_t)(p0 + pt) * 512 + 128 + o] = f2bf(mx);
  }
}

// ---------------- K4: sn stage, 4 points/block, M=80 -------------------------
__global__ __launch_bounds__(256) void sn_stage(
    const int* __restrict__ idx2, const unsigned short* __restrict__ wb,
    const float* __restrict__ bias, unsigned short* __restrict__ featb) {
  __shared__ unsigned short s_a[80][264];   // row stride 528 B (16B-aligned)
  __shared__ int s_nbf[80];
  int p0 = blockIdx.x * 4;
  int b = p0 >> 12, n0 = p0 & 4095;
  int bb = b << 12;
  int t = threadIdx.x;
  int lane = t & 63, wave = t >> 6;
  if (t < 80) s_nbf[t] = idx2[p0 * 20 + t];
  __syncthreads();
  {
    int cc = (t & 31) * 8;                  // uniform per-thread
    int r00 = t >> 5;
    #pragma unroll
    for (int it = 0; it < 10; it++) {
      int row = r00 + it * 8;
      const unsigned short* src = (cc < 128)
        ? featb + (size_t)(bb + s_nbf[row]) * 512 + 128 + cc
        : featb + (size_t)(bb + n0 + row / 20) * 512 + cc;   // 128+(cc-128)
      *(short8*)&s_a[row][cc] = *(const short8*)src;
    }
  }
  __syncthreads();
  int quad = lane >> 4, mrow = lane & 15;
  int nblock = wave * 64;
  floatx4 acc[5][4];
  #pragma unroll
  for (int mt = 0; mt < 5; mt++)
    #pragma unroll
    for (int ns = 0; ns < 4; ns++) acc[mt][ns] = (floatx4)0.f;
  #pragma unroll
  for (int ks = 0; ks < 8; ks++) {
    int k0 = ks * 32 + quad * 8;
    short8 w[4];
    #pragma unroll
    for (int ns = 0; ns < 4; ns++)
      w[ns] = *(const short8*)(wb + (nblock + ns * 16 + mrow) * 256 + k0);
    #pragma unroll
    for (int mt = 0; mt < 5; mt++) {
      short8 a = *(short8*)&s_a[mt * 16 + mrow][k0];
      #pragma unroll
      for (int ns = 0; ns < 4; ns++)
        acc[mt][ns] = mfma_bf16(a, w[ns], acc[mt][ns]);
    }
  }
  __syncthreads();                          // all s_a reads done
  #pragma unroll
  for (int ns = 0; ns < 4; ns++) {
    int o = nblock + ns * 16 + mrow;
    float bz = bias[o];
    #pragma unroll
    for (int mt = 0; mt < 5; mt++)
      #pragma unroll
      for (int r = 0; r < 4; r++)
        s_a[mt * 16 + quad * 4 + r][o] = f2bf(fmaxf(acc[mt][ns][r] + bz, 0.f));
  }
  __syncthreads();
  #pragma unroll
  for (int it = 0; it < 4; it++) {
    int e = t + it * 256;                   // 1024 outputs
    int pt = e >> 8, o = e & 255;
    float mx = 0.f;
    for (int k = 0; k < 20; k++) mx = fmaxf(mx, bf2f(s_a[pt * 20 + k][o]));
    featb[(size_t)(p0 + pt) * 512 + 256 + o] = f2bf(mx);
  }
}

// ---------------- K5: conv3 GEMM ---------------------------------------------
__global__ __launch_bounds__(256) void conv3_gemm(
    const unsigned short* __restrict__ w3b, const unsigned short* __restrict__ featb,
    const float* __restrict__ b3, float* __restrict__ out) {
  __shared__ unsigned short s_a[128][40];
  __shared__ unsigned short s_b[128][40];
  int o0 = blockIdx.x * 128, p0 = blockIdx.y * 128;
  int t = threadIdx.x, lane = t & 63, wave = t >> 6;
  int wy = wave >> 1, wx = wave & 1;
  int quad = lane >> 4, l15 = lane & 15;
  floatx4 acc[4][4];
  #pragma unroll
  for (int i = 0; i < 4; i++)
    #pragma unroll
    for (int j = 0; j < 4; j++) acc[i][j] = (floatx4)0.f;
  for (int kc = 0; kc < 16; kc++) {
    __syncthreads();
    for (int e = t; e < 512; e += 256) {
      int r = e >> 2, c8 = (e & 3) * 8;
      *(short8*)&s_a[r][c8] = *(const short8*)(w3b + (size_t)(o0 + r) * 512 + kc * 32 + c8);
    }
    for (int e = t; e < 512; e += 256) {
      int r = e >> 2, c8 = (e & 3) * 8;
      *(short8*)&s_b[r][c8] = *(const short8*)(featb + (size_t)(p0 + r) * 512 + kc * 32 + c8);
    }
    __syncthreads();
    int k0 = quad * 8;
    short8 af[4], bfr[4];
    #pragma unroll
    for (int i = 0; i < 4; i++) af[i] = *(short8*)&s_a[wy * 64 + i * 16 + l15][k0];
    #pragma unroll
    for (int j = 0; j < 4; j++) bfr[j] = *(short8*)&s_b[wx * 64 + j * 16 + l15][k0];
    #pragma unroll
    for (int i = 0; i < 4; i++)
      #pragma unroll
      for (int j = 0; j < 4; j++) acc[i][j] = mfma_bf16(af[i], bfr[j], acc[i][j]);
  }
  #pragma unroll
  for (int i = 0; i < 4; i++)
    #pragma unroll
    for (int j = 0; j < 4; j++) {
      int pl = p0 + wx * 64 + j * 16 + l15;
      int bI = pl >> 12, n = pl & 4095;
      #pragma unroll
      for (int r = 0; r < 4; r++) {
        int o = o0 + wy * 64 + i * 16 + quad * 4 + r;
        out[(size_t)(bI * 1024 + o) * 4096 + n] = fmaxf(acc[i][j][r] + b3[o], 0.f);
      }
    }
}

// ---------------- launcher ---------------------------------------------------
extern "C" void kernel_launch(void* const* d_in, const int* in_sizes, int n_in,
                              void* d_out, int out_size, void* d_ws, size_t ws_size,
                              hipStream_t stream) {
  const float* x    = (const float*)d_in[0];
  const float* w1   = (const float*)d_in[1];
  const float* b1   = (const float*)d_in[2];
  const float* w2   = (const float*)d_in[3];
  const float* b2   = (const float*)d_in[4];
  const float* wdg1 = (const float*)d_in[5];
  const float* bdg1 = (const float*)d_in[6];
  const float* wdg2 = (const float*)d_in[7];
  const float* bdg2 = (const float*)d_in[8];
  const float* wsn1 = (const float*)d_in[9];
  const float* bsn1 = (const float*)d_in[10];
  const float* w3   = (const float*)d_in[11];
  const float* b3   = (const float*)d_in[12];

  float* ws = (float*)d_ws;                 // offsets in float slots
  unsigned short* hlo16 = (unsigned short*)ws;               // 2,097,152 bf16 (1,048,576 slots)
  float* hh = ws + 2097152;                 //    32,768
  float* cc = ws + 2129920;                 //    32,768
  int* idx1 = (int*)(ws + 2162688);         //   655,360
  int* idx2 = (int*)(ws + 2818048);         //   655,360
  unsigned short* featb = (unsigned short*)(ws + 3473408);   // 16,777,216 bf16
  unsigned short* wdg1b = (unsigned short*)(ws + 11862016);
  unsigned short* wdg2b = (unsigned short*)(ws + 11870208);
  unsigned short* wsn1b = (unsigned short*)(ws + 11878400);
  unsigned short* w3b   = (unsigned short*)(ws + 11911168);
  unsigned short* hb16  = (unsigned short*)(ws + 12173312); // 2,097,152 bf16

  cvt_weights<<<2048, 256, 0, stream>>>(wdg1, wdg1b, wdg2, wdg2b,
                                        wsn1, wsn1b, w3, w3b);
  conv12<<<8192, 256, 0, stream>>>(x, w1, b1, w2, b2, hb16, hlo16, hh, cc);
  knn64_mfma<<<dim3(64, 8), 256, 0, stream>>>(hb16, hlo16, hh, idx1);
  knn_topk<3><<<dim3(64, 8), 256, 0, stream>>>(x, cc, idx2);
  dg_stage<<<8192, 256, 0, stream>>>(hb16, idx1, wdg1b, bdg1, wdg2b, bdg2, featb);
  sn_stage<<<8192, 256, 0, stream>>>(idx2, wsn1b, bsn1, featb);
  conv3_gemm<<<dim3(8, 256), 256, 0, stream>>>(w3b, featb, b3, (float*)d_out);
}

// Round 5
// 991.501 us; speedup vs baseline: 1.1794x; 1.0421x over previous
//
#include <hip/hip_runtime.h>
#include <stdint.h>

// LPDNet forward on gfx950.
// Layout decisions:
//   hb16/hlo16 : (B,N,64) bf16 hi/lo split of h -> MFMA knn + pure-copy gather
//   featb : (B,N,512) bf16 rows -> [x1 | x2 | x3]; feeds conv3 GEMM and x2 gather
//   idx1/idx2 : (B,N,20) int32
// Graph-conv trick: W·[nbr-ctr | ctr] == W'·[nbr | ctr] with W' = [Wn | Wc-Wn]
// (transformed once in cvt_weights) -> gather staging is pure short8 copies.
// knn64: inner products via 4-term split-bf16 MFMA (hi/lo), residual ~1e-8.
// bf16 conv path (fp32 accum); tolerance is 2% of max|ref|.
// R8: m-tile 64->128 in knn64 (barriers 128->64) + score = acc-0.5*xxM.
// Verified: knn64 dropped out of top-5 (<259us), total 1077->1033.
// R9: same proven transform applied to knn_topk<3> (the new top kernel at
// 260us, VALUBusy 56%, occupancy grid-capped): 128-wide tiles (32 tiles,
// barriers 128->64), acc[4][8] compute mapping, 32-bit selection masks.
// LDS 20->37KB (free: residency is grid-capped at 2 blocks/CU).
// R10: resubmit of R9 verbatim -- previous round's bench was an infra
// failure (container died twice, no pytest/profile); code audit found no
// fault/hang mechanism (bounds, alignment, LDS size, loop caps all checked).

#define NB 8
#define NP 4096
#define NPTS (NB*NP)

typedef float  floatx4 __attribute__((ext_vector_type(4)));
typedef short  short8  __attribute__((ext_vector_type(8)));

__device__ __forceinline__ unsigned short f2bf(float f) {
  union { float f; uint32_t u; } v; v.f = f;
  uint32_t r = v.u + 0x7fffu + ((v.u >> 16) & 1u);   // RNE
  return (unsigned short)(r >> 16);
}
__device__ __forceinline__ float bf2f(unsigned short h) {
  union { uint32_t u; float f; } v; v.u = ((uint32_t)h) << 16;
  return v.f;
}

__device__ __forceinline__ floatx4 mfma_bf16(short8 a, short8 b, floatx4 c) {
  return __builtin_amdgcn_mfma_f32_16x16x32_bf16(a, b, c, 0, 0, 0);
}

// ---------------- K0: weight conversion + graph-fold transform ---------------
__global__ void cvt_weights(const float* wdg1, unsigned short* wdg1b,
                            const float* wdg2, unsigned short* wdg2b,
                            const float* wsn1, unsigned short* wsn1b,
                            const float* w3, unsigned short* w3b) {
  int i = blockIdx.x * 256 + threadIdx.x;
  if (i < 16384) {                       // wdg1' = [Wn | Wc-Wn], C=64
    int c = i & 127;
    wdg1b[i] = f2bf(wdg1[i] - (c >= 64 ? wdg1[i - 64] : 0.f));
  }
  if (i < 16384) wdg2b[i] = f2bf(wdg2[i]);
  if (i < 65536) {                       // wsn1' = [Wn | Wc-Wn], C=128
    int c = i & 255;
    wsn1b[i] = f2bf(wsn1[i] - (c >= 128 ? wsn1[i - 128] : 0.f));
  }
  if (i < 524288) w3b[i] = f2bf(w3[i]);
}

// ---------------- K1: conv1+relu, conv2+relu -> h hi/lo bf16, xx sums --------
__global__ __launch_bounds__(256) void conv12(
    const float* __restrict__ xin, const float* __restrict__ w1,
    const float* __restrict__ b1, const float* __restrict__ w2,
    const float* __restrict__ b2,
    unsigned short* __restrict__ hb16, unsigned short* __restrict__ hlo16,
    float* __restrict__ hh, float* __restrict__ cc) {
  int wave = threadIdx.x >> 6, lane = threadIdx.x & 63;
  int p = blockIdx.x * 4 + wave;                    // grid 8192
  __shared__ float s_h1[4][64];
  const float* xp = xin + p * 3;
  float c0 = xp[0], c1 = xp[1], c2 = xp[2];
  float v = b1[lane] + w1[lane*3+0]*c0 + w1[lane*3+1]*c1 + w1[lane*3+2]*c2;
  s_h1[wave][lane] = fmaxf(v, 0.f);
  __syncthreads();
  float acc = b2[lane];
  const float* wr = w2 + lane * 64;
  #pragma unroll
  for (int c = 0; c < 64; c += 4) {
    floatx4 w4 = *(const floatx4*)(wr + c);
    acc += w4[0]*s_h1[wave][c]   + w4[1]*s_h1[wave][c+1]
         + w4[2]*s_h1[wave][c+2] + w4[3]*s_h1[wave][c+3];
  }
  acc = fmaxf(acc, 0.f);
  unsigned short hi = f2bf(acc);
  hb16[p*64 + lane] = hi;
  hlo16[p*64 + lane] = f2bf(acc - bf2f(hi));
  float sq = acc * acc;
  #pragma unroll
  for (int off = 32; off; off >>= 1) sq += __shfl_xor(sq, off, 64);
  if (lane == 0) { hh[p] = sq; cc[p] = c0*c0 + c1*c1 + c2*c2; }
}

// ---------------- K2a: knn C=64 via split-bf16 MFMA + ballot top-20 ----------
// 64 rows/block, single pass over all 4096 candidates in 32 tiles of 128.
// Wave w owns rows 16w..16w+15: A-frags (hi/lo, 2 k-steps) loaded once from
// global. Per m-tile: stage 128 rows hi/lo (pure copies) + 0.5*xxM; 8 n-tiles
// x 2 k-steps x 4 chained MFMAs; score = acc - 0.5*xxM written to dots in C/D
// layout (row=quad*4+reg, col=lane&15). Selection = R5 ballot machinery with
// 32-bit masks (sub covers 32 cols); racy-LDS tau gate (proven).
__global__ __launch_bounds__(256) void knn64_mfma(
    const unsigned short* __restrict__ Hhi, const unsigned short* __restrict__ Hlo,
    const float* __restrict__ XX, int* __restrict__ idx_out) {
  __shared__ unsigned short mhi[128][72];  // stride 72: 16B-aligned rows
  __shared__ unsigned short mlo[128][72];
  __shared__ float dots[64][132];
  __shared__ float xxMh[128];
  __shared__ float tau[64];
  int b = blockIdx.y;
  int r0 = blockIdx.x * 64;
  int t = threadIdx.x;
  int lane = t & 63, wave = t >> 6;
  int quad = lane >> 4, l15 = lane & 15;
  const unsigned short* Hhib = Hhi + (size_t)b * NP * 64;
  const unsigned short* Hlob = Hlo + (size_t)b * NP * 64;
  short8 ahi[2], alo[2];
  {
    const unsigned short* pr = Hhib + (size_t)(r0 + wave * 16 + l15) * 64 + quad * 8;
    const unsigned short* pl = Hlob + (size_t)(r0 + wave * 16 + l15) * 64 + quad * 8;
    ahi[0] = *(const short8*)pr; ahi[1] = *(const short8*)(pr + 32);
    alo[0] = *(const short8*)pl; alo[1] = *(const short8*)(pl + 32);
  }
  if (t < 64) tau[t] = -__builtin_inff();

  float lv[20]; int li[20];
  #pragma unroll
  for (int s = 0; s < 20; s++) { lv[s] = -__builtin_inff(); li[s] = 0x7fffffff; }
  float minval = -__builtin_inff(); int minpos = 0;
  int row = t >> 2, sub = t & 3;

  for (int mt = 0; mt < NP / 128; mt++) {
    int m0 = mt * 128;
    {                                      // stage 128-row m-tile hi/lo
      int hf = t & 1, r = (t >> 1) & 127;  // 2 threads per row, 64B each
      int c0 = hf * 32;
      const unsigned short* sh = Hhib + (size_t)(m0 + r) * 64 + c0;
      const unsigned short* sl = Hlob + (size_t)(m0 + r) * 64 + c0;
      *(short8*)&mhi[r][c0]      = *(const short8*)sh;
      *(short8*)&mhi[r][c0 + 8]  = *(const short8*)(sh + 8);
      *(short8*)&mhi[r][c0 + 16] = *(const short8*)(sh + 16);
      *(short8*)&mhi[r][c0 + 24] = *(const short8*)(sh + 24);
      *(short8*)&mlo[r][c0]      = *(const short8*)sl;
      *(short8*)&mlo[r][c0 + 8]  = *(const short8*)(sl + 8);
      *(short8*)&mlo[r][c0 + 16] = *(const short8*)(sl + 16);
      *(short8*)&mlo[r][c0 + 24] = *(const short8*)(sl + 24);
    }
    if (t < 128) xxMh[t] = 0.5f * XX[b * NP + m0 + t];
    __syncthreads();                       // staging visible; prev select done
    #pragma unroll
    for (int nt = 0; nt < 8; nt++) {
      floatx4 acc = (floatx4)0.f;
      #pragma unroll
      for (int ks = 0; ks < 2; ks++) {
        int k0 = ks * 32 + quad * 8;
        short8 bhi = *(short8*)&mhi[nt * 16 + l15][k0];
        short8 blo = *(short8*)&mlo[nt * 16 + l15][k0];
        acc = mfma_bf16(ahi[ks], bhi, acc);
        acc = mfma_bf16(ahi[ks], blo, acc);
        acc = mfma_bf16(alo[ks], bhi, acc);
        acc = mfma_bf16(alo[ks], blo, acc);
      }
      int colg = nt * 16 + l15;
      float xm = xxMh[colg];
      #pragma unroll
      for (int r = 0; r < 4; r++) {
        int mr = wave * 16 + quad * 4 + r;
        dots[mr][colg] = acc[r] - xm;
      }
    }
    __syncthreads();                       // dots ready
    // ---- R5 ballot selection, 32 cols per sub-thread ----
    float gate = fmaxf(minval, tau[row]);
    floatx4 dv[8];
    #pragma unroll
    for (int q = 0; q < 8; q++) dv[q] = *(floatx4*)&dots[row][sub * 32 + q * 4];
    uint32_t mask = 0;
    #pragma unroll
    for (int q = 0; q < 8; q++)
      #pragma unroll
      for (int j = 0; j < 4; j++)
        if (dv[q][j] > gate) mask |= 1u << (q * 4 + j);
    #pragma clang loop unroll(disable)
    for (int round = 0; round < 32; round++) {
      if (!__any(mask != 0)) break;
      if (mask) {
        int i = __builtin_ctz(mask); mask &= mask - 1;
        float v = dots[row][sub * 32 + i];
        if (v > minval) {
          int gi = m0 + sub * 32 + i;
          #pragma unroll
          for (int s = 0; s < 20; s++)
            if (s == minpos) { lv[s] = v; li[s] = gi; }
          minval = __builtin_inff();
          #pragma unroll
          for (int s = 0; s < 20; s++)
            if (lv[s] < minval) { minval = lv[s]; minpos = s; }
        }
      }
    }
    tau[row] = fmaxf(tau[row], minval);
  }
  int base = (b * NP + r0 + row) * 20;
  for (int sel = 0; sel < 20; sel++) {
    float mybv = -__builtin_inff(); int mybi = 0x7fffffff, mybs = 0;
    #pragma unroll
    for (int s = 0; s < 20; s++) {
      bool better = lv[s] > mybv || (lv[s] == mybv && li[s] < mybi);
      if (better) { mybv = lv[s]; mybi = li[s]; mybs = s; }
    }
    float bv = mybv; int bi = mybi;
    float ov = __shfl_xor(bv, 1, 64); int oi = __shfl_xor(bi, 1, 64);
    if (ov > bv || (ov == bv && oi < bi)) { bv = ov; bi = oi; }
    ov = __shfl_xor(bv, 2, 64); oi = __shfl_xor(bi, 2, 64);
    if (ov > bv || (ov == bv && oi < bi)) { bv = ov; bi = oi; }
    if (sub == 0) idx_out[base + sel] = bi;
    if (bi == mybi) {
      #pragma unroll
      for (int s = 0; s < 20; s++)
        if (s == mybs) { lv[s] = -__builtin_inff(); li[s] = 0x7fffffff; }
    }
  }
}

// ---------------- K2b: knn C=3 (fp32 vector path) ----------------------------
// R9: 128-wide tiles (32 tiles, half the barriers), acc[4][8] mapping,
// 32-bit selection masks -- the R8-proven knn64 transform. Score shift kept.
template<int C>
__global__ __launch_bounds__(256) void knn_topk(
    const float* __restrict__ X, const float* __restrict__ XX,
    int* __restrict__ idx_out) {
  __shared__ float rowsT[C][68];
  __shared__ float mT[C][132];
  __shared__ float dots[64][132];
  __shared__ float xxMh[128];
  __shared__ float tau[64];
  int b = blockIdx.y;
  int r0 = blockIdx.x * 64;
  int t = threadIdx.x;
  const float* Xb = X + (size_t)b * NP * C;
  for (int e = t; e < C * 64; e += 256) {
    int r = e / C, c = e - r * C;
    rowsT[c][r] = Xb[(r0 + r) * C + c];
  }
  if (t < 64) tau[t] = -__builtin_inff();

  float lv[20]; int li[20];
  #pragma unroll
  for (int s = 0; s < 20; s++) { lv[s] = -__builtin_inff(); li[s] = 0x7fffffff; }
  float minval = -__builtin_inff(); int minpos = 0;

  int tm = t & 15, tr = t >> 4;
  int row = t >> 2, sub = t & 3;

  for (int mt = 0; mt < NP / 128; mt++) {
    int m0 = mt * 128;
    for (int e = t; e < C * 128; e += 256) {
      int r = e / C, c = e - r * C;
      mT[c][r] = Xb[(m0 + r) * C + c];
    }
    if (t < 128) xxMh[t] = 0.5f * XX[b * NP + m0 + t];
    __syncthreads();
    float acc[4][8];
    #pragma unroll
    for (int i = 0; i < 4; i++)
      #pragma unroll
      for (int j = 0; j < 8; j++) acc[i][j] = 0.f;
    for (int c = 0; c < C; c++) {
      floatx4 av  = *(floatx4*)&rowsT[c][tr * 4];
      floatx4 bv0 = *(floatx4*)&mT[c][tm * 8];
      floatx4 bv1 = *(floatx4*)&mT[c][tm * 8 + 4];
      #pragma unroll
      for (int i = 0; i < 4; i++)
        #pragma unroll
        for (int j = 0; j < 4; j++) {
          acc[i][j]     += av[i] * bv0[j];
          acc[i][j + 4] += av[i] * bv1[j];
        }
    }
    #pragma unroll
    for (int i = 0; i < 4; i++) {
      floatx4 sv0, sv1;
      #pragma unroll
      for (int j = 0; j < 4; j++) {
        sv0[j] = acc[i][j]     - xxMh[tm*8 + j];
        sv1[j] = acc[i][j + 4] - xxMh[tm*8 + 4 + j];
      }
      *(floatx4*)&dots[tr*4 + i][tm*8]     = sv0;
      *(floatx4*)&dots[tr*4 + i][tm*8 + 4] = sv1;
    }
    __syncthreads();
    // ---- selection, 32 cols per sub-thread ----
    float gate = fmaxf(minval, tau[row]);
    floatx4 dv[8];
    #pragma unroll
    for (int q = 0; q < 8; q++) dv[q] = *(floatx4*)&dots[row][sub * 32 + q * 4];
    uint32_t mask = 0;
    #pragma unroll
    for (int q = 0; q < 8; q++)
      #pragma unroll
      for (int j = 0; j < 4; j++)
        if (dv[q][j] > gate) mask |= 1u << (q * 4 + j);
    #pragma clang loop unroll(disable)
    for (int round = 0; round < 32; round++) {
      if (!__any(mask != 0)) break;
      if (mask) {
        int i = __builtin_ctz(mask); mask &= mask - 1;
        float v = dots[row][sub * 32 + i];
        if (v > minval) {
          int gi = m0 + sub * 32 + i;
          #pragma unroll
          for (int s = 0; s < 20; s++)
            if (s == minpos) { lv[s] = v; li[s] = gi; }
          minval = __builtin_inff();
          #pragma unroll
          for (int s = 0; s < 20; s++)
            if (lv[s] < minval) { minval = lv[s]; minpos = s; }
        }
      }
    }
    tau[row] = fmaxf(tau[row], minval);
  }
  int base = (b * NP + r0 + row) * 20;
  for (int sel = 0; sel < 20; sel++) {
    float mybv = -__builtin_inff(); int mybi = 0x7fffffff, mybs = 0;
    #pragma unroll
    for (int s = 0; s < 20; s++) {
      bool better = lv[s] > mybv || (lv[s] == mybv && li[s] < mybi);
      if (better) { mybv = lv[s]; mybi = li[s]; mybs = s; }
    }
    float bv = mybv; int bi = mybi;
    float ov = __shfl_xor(bv, 1, 64); int oi = __shfl_xor(bi, 1, 64);
    if (ov > bv || (ov == bv && oi < bi)) { bv = ov; bi = oi; }
    ov = __shfl_xor(bv, 2, 64); oi = __shfl_xor(bi, 2, 64);
    if (ov > bv || (ov == bv && oi < bi)) { bv = ov; bi = oi; }
    if (sub == 0) idx_out[base + sel] = bi;
    if (bi == mybi) {
      #pragma unroll
      for (int s = 0; s < 20; s++)
        if (s == mybs) { lv[s] = -__builtin_inff(); li[s] = 0x7fffffff; }
    }
  }
}

// ---------------- K3: dg stage, 4 points/block, M=80 (zero padding) ----------
__global__ __launch_bounds__(256) void dg_stage(
    const unsigned short* __restrict__ hb16, const int* __restrict__ idx1,
    const unsigned short* __restrict__ w1b, const float* __restrict__ bia1,
    const unsigned short* __restrict__ w2b, const float* __restrict__ bia2,
    unsigned short* __restrict__ featb) {
  __shared__ unsigned short s_a[80][136];   // row stride 272 B (16B-aligned)
  __shared__ unsigned short s_v[80][136];
  __shared__ int s_nbf[80];
  int p0 = blockIdx.x * 4;                  // grid 8192; 4 pts share batch b
  int b = p0 >> 12, n0 = p0 & 4095;
  int t = threadIdx.x;
  int lane = t & 63, wave = t >> 6;
  if (t < 80) s_nbf[t] = idx1[p0 * 20 + t];
  __syncthreads();
  const unsigned short* hbb = hb16 + (size_t)b * NP * 64;
  {
    int cc = (t & 15) * 8;                  // uniform per-thread across iters
    int r00 = t >> 4;
    #pragma unroll
    for (int it = 0; it < 5; it++) {
      int row = r00 + it * 16;
      const unsigned short* src = (cc < 64)
        ? hbb + (size_t)s_nbf[row] * 64 + cc
        : hbb + (size_t)(n0 + row / 20) * 64 + (cc - 64);
      *(short8*)&s_a[row][cc] = *(const short8*)src;
    }
  }
  __syncthreads();
  int quad = lane >> 4, mrow = lane & 15;
  int nblock = wave * 32;
  // ---- dg1: A=s_a(80x128), W=w1b' ----
  {
    floatx4 acc[5][2];
    #pragma unroll
    for (int mt = 0; mt < 5; mt++) { acc[mt][0] = (floatx4)0.f; acc[mt][1] = (floatx4)0.f; }
    #pragma unroll
    for (int ks = 0; ks < 4; ks++) {
      int k0 = ks * 32 + quad * 8;
      short8 w0 = *(const short8*)(w1b + (nblock + mrow) * 128 + k0);
      short8 w1v = *(const short8*)(w1b + (nblock + 16 + mrow) * 128 + k0);
      #pragma unroll
      for (int mt = 0; mt < 5; mt++) {
        short8 a = *(short8*)&s_a[mt * 16 + mrow][k0];
        acc[mt][0] = mfma_bf16(a, w0, acc[mt][0]);
        acc[mt][1] = mfma_bf16(a, w1v, acc[mt][1]);
      }
    }
    #pragma unroll
    for (int ns = 0; ns < 2; ns++) {
      int o = nblock + ns * 16 + mrow;
      float bz = bia1[o];
      #pragma unroll
      for (int mt = 0; mt < 5; mt++)
        #pragma unroll
        for (int r = 0; r < 4; r++)
          s_v[mt * 16 + quad * 4 + r][o] = f2bf(fmaxf(acc[mt][ns][r] + bz, 0.f));
    }
  }
  __syncthreads();                          // s_v ready; all s_a reads done
  #pragma unroll
  for (int it = 0; it < 2; it++) {
    int e = t + it * 256;                   // 512 outputs
    int pt = e >> 7, o = e & 127;
    float mx = 0.f;
    for (int k = 0; k < 20; k++) mx = fmaxf(mx, bf2f(s_v[pt * 20 + k][o]));
    featb[(size_t)(p0 + pt) * 512 + o] = f2bf(mx);
  }
  // ---- dg2: A=s_v(80x128), W=w2b, relu -> s_a (reuse) ----
  {
    floatx4 acc[5][2];
    #pragma unroll
    for (int mt = 0; mt < 5; mt++) { acc[mt][0] = (floatx4)0.f; acc[mt][1] = (floatx4)0.f; }
    #pragma unroll
    for (int ks = 0; ks < 4; ks++) {
      int k0 = ks * 32 + quad * 8;
      short8 w0 = *(const short8*)(w2b + (nblock + mrow) * 128 + k0);
      short8 w1v = *(const short8*)(w2b + (nblock + 16 + mrow) * 128 + k0);
      #pragma unroll
      for (int mt = 0; mt < 5; mt++) {
        short8 a = *(short8*)&s_v[mt * 16 + mrow][k0];
        acc[mt][0] = mfma_bf16(a, w0, acc[mt][0]);
        acc[mt][1] = mfma_bf16(a, w1v, acc[mt][1]);
      }
    }
    #pragma unroll
    for (int ns = 0; ns < 2; ns++) {
      int o = nblock + ns * 16 + mrow;
      float bz = bia2[o];
      #pragma unroll
      for (int mt = 0; mt < 5; mt++)
        #pragma unroll
        for (int r = 0; r < 4; r++)
          s_a[mt * 16 + quad * 4 + r][o] = f2bf(fmaxf(acc[mt][ns][r] + bz, 0.f));
    }
  }
  __syncthreads();
  #pragma unroll
  for (int it = 0; it < 2; it++) {
    int e = t + it * 256;
    int pt = e >> 7, o = e & 127;
    float mx = 0.f;
    for (int k = 0; k < 20; k++) mx = fmaxf(mx, bf2f(s_a[pt * 20 + k][o]));
    featb[(size_t)(p0 + pt) * 512 + 128 + o] = f2bf(mx);
  }
}

// ---------------- K4: sn stage, 4 points/block, M=80 -------------------------
__global__ __launch_bounds__(256) void sn_stage(
    const int* __restrict__ idx2, const unsigned short* __restrict__ wb,
    const float* __restrict__ bias, unsigned short* __restrict__ featb) {
  __shared__ unsigned short s_a[80][264];   // row stride 528 B (16B-aligned)
  __shared__ int s_nbf[80];
  int p0 = blockIdx.x * 4;
  int b = p0 >> 12, n0 = p0 & 4095;
  int bb = b << 12;
  int t = threadIdx.x;
  int lane = t & 63, wave = t >> 6;
  if (t < 80) s_nbf[t] = idx2[p0 * 20 + t];
  __syncthreads();
  {
    int cc = (t & 31) * 8;                  // uniform per-thread
    int r00 = t >> 5;
    #pragma unroll
    for (int it = 0; it < 10; it++) {
      int row = r00 + it * 8;
      const unsigned short* src = (cc < 128)
        ? featb + (size_t)(bb + s_nbf[row]) * 512 + 128 + cc
        : featb + (size_t)(bb + n0 + row / 20) * 512 + cc;   // 128+(cc-128)
      *(short8*)&s_a[row][cc] = *(const short8*)src;
    }
  }
  __syncthreads();
  int quad = lane >> 4, mrow = lane & 15;
  int nblock = wave * 64;
  floatx4 acc[5][4];
  #pragma unroll
  for (int mt = 0; mt < 5; mt++)
    #pragma unroll
    for (int ns = 0; ns < 4; ns++) acc[mt][ns] = (floatx4)0.f;
  #pragma unroll
  for (int ks = 0; ks < 8; ks++) {
    int k0 = ks * 32 + quad * 8;
    short8 w[4];
    #pragma unroll
    for (int ns = 0; ns < 4; ns++)
      w[ns] = *(const short8*)(wb + (nblock + ns * 16 + mrow) * 256 + k0);
    #pragma unroll
    for (int mt = 0; mt < 5; mt++) {
      short8 a = *(short8*)&s_a[mt * 16 + mrow][k0];
      #pragma unroll
      for (int ns = 0; ns < 4; ns++)
        acc[mt][ns] = mfma_bf16(a, w[ns], acc[mt][ns]);
    }
  }
  __syncthreads();                          // all s_a reads done
  #pragma unroll
  for (int ns = 0; ns < 4; ns++) {
    int o = nblock + ns * 16 + mrow;
    float bz = bias[o];
    #pragma unroll
    for (int mt = 0; mt < 5; mt++)
      #pragma unroll
      for (int r = 0; r < 4; r++)
        s_a[mt * 16 + quad * 4 + r][o] = f2bf(fmaxf(acc[mt][ns][r] + bz, 0.f));
  }
  __syncthreads();
  #pragma unroll
  for (int it = 0; it < 4; it++) {
    int e = t + it * 256;                   // 1024 outputs
    int pt = e >> 8, o = e & 255;
    float mx = 0.f;
    for (int k = 0; k < 20; k++) mx = fmaxf(mx, bf2f(s_a[pt * 20 + k][o]));
    featb[(size_t)(p0 + pt) * 512 + 256 + o] = f2bf(mx);
  }
}

// ---------------- K5: conv3 GEMM ---------------------------------------------
__global__ __launch_bounds__(256) void conv3_gemm(
    const unsigned short* __restrict__ w3b, const unsigned short* __restrict__ featb,
    const float* __restrict__ b3, float* __restrict__ out) {
  __shared__ unsigned short s_a[128][40];
  __shared__ unsigned short s_b[128][40];
  int o0 = blockIdx.x * 128, p0 = blockIdx.y * 128;
  int t = threadIdx.x, lane = t & 63, wave = t >> 6;
  int wy = wave >> 1, wx = wave & 1;
  int quad = lane >> 4, l15 = lane & 15;
  floatx4 acc[4][4];
  #pragma unroll
  for (int i = 0; i < 4; i++)
    #pragma unroll
    for (int j = 0; j < 4; j++) acc[i][j] = (floatx4)0.f;
  for (int kc = 0; kc < 16; kc++) {
    __syncthreads();
    for (int e = t; e < 512; e += 256) {
      int r = e >> 2, c8 = (e & 3) * 8;
      *(short8*)&s_a[r][c8] = *(const short8*)(w3b + (size_t)(o0 + r) * 512 + kc * 32 + c8);
    }
    for (int e = t; e < 512; e += 256) {
      int r = e >> 2, c8 = (e & 3) * 8;
      *(short8*)&s_b[r][c8] = *(const short8*)(featb + (size_t)(p0 + r) * 512 + kc * 32 + c8);
    }
    __syncthreads();
    int k0 = quad * 8;
    short8 af[4], bfr[4];
    #pragma unroll
    for (int i = 0; i < 4; i++) af[i] = *(short8*)&s_a[wy * 64 + i * 16 + l15][k0];
    #pragma unroll
    for (int j = 0; j < 4; j++) bfr[j] = *(short8*)&s_b[wx * 64 + j * 16 + l15][k0];
    #pragma unroll
    for (int i = 0; i < 4; i++)
      #pragma unroll
      for (int j = 0; j < 4; j++) acc[i][j] = mfma_bf16(af[i], bfr[j], acc[i][j]);
  }
  #pragma unroll
  for (int i = 0; i < 4; i++)
    #pragma unroll
    for (int j = 0; j < 4; j++) {
      int pl = p0 + wx * 64 + j * 16 + l15;
      int bI = pl >> 12, n = pl & 4095;
      #pragma unroll
      for (int r = 0; r < 4; r++) {
        int o = o0 + wy * 64 + i * 16 + quad * 4 + r;
        out[(size_t)(bI * 1024 + o) * 4096 + n] = fmaxf(acc[i][j][r] + b3[o], 0.f);
      }
    }
}

// ---------------- launcher ---------------------------------------------------
extern "C" void kernel_launch(void* const* d_in, const int* in_sizes, int n_in,
                              void* d_out, int out_size, void* d_ws, size_t ws_size,
                              hipStream_t stream) {
  const float* x    = (const float*)d_in[0];
  const float* w1   = (const float*)d_in[1];
  const float* b1   = (const float*)d_in[2];
  const float* w2   = (const float*)d_in[3];
  const float* b2   = (const float*)d_in[4];
  const float* wdg1 = (const float*)d_in[5];
  const float* bdg1 = (const float*)d_in[6];
  const float* wdg2 = (const float*)d_in[7];
  const float* bdg2 = (const float*)d_in[8];
  const float* wsn1 = (const float*)d_in[9];
  const float* bsn1 = (const float*)d_in[10];
  const float* w3   = (const float*)d_in[11];
  const float* b3   = (const float*)d_in[12];

  float* ws = (float*)d_ws;                 // offsets in float slots
  unsigned short* hlo16 = (unsigned short*)ws;               // 2,097,152 bf16 (1,048,576 slots)
  float* hh = ws + 2097152;                 //    32,768
  float* cc = ws + 2129920;                 //    32,768
  int* idx1 = (int*)(ws + 2162688);         //   655,360
  int* idx2 = (int*)(ws + 2818048);         //   655,360
  unsigned short* featb = (unsigned short*)(ws + 3473408);   // 16,777,216 bf16
  unsigned short* wdg1b = (unsigned short*)(ws + 11862016);
  unsigned short* wdg2b = (unsigned short*)(ws + 11870208);
  unsigned short* wsn1b = (unsigned short*)(ws + 11878400);
  unsigned short* w3b   = (unsigned short*)(ws + 11911168);
  unsigned short* hb16  = (unsigned short*)(ws + 12173312); // 2,097,152 bf16

  cvt_weights<<<2048, 256, 0, stream>>>(wdg1, wdg1b, wdg2, wdg2b,
                                        wsn1, wsn1b, w3, w3b);
  conv12<<<8192, 256, 0, stream>>>(x, w1, b1, w2, b2, hb16, hlo16, hh, cc);
  knn64_mfma<<<dim3(64, 8), 256, 0, stream>>>(hb16, hlo16, hh, idx1);
  knn_topk<3><<<dim3(64, 8), 256, 0, stream>>>(x, cc, idx2);
  dg_stage<<<8192, 256, 0, stream>>>(hb16, idx1, wdg1b, bdg1, wdg2b, bdg2, featb);
  sn_stage<<<8192, 256, 0, stream>>>(idx2, wsn1b, bsn1, featb);
  conv3_gemm<<<dim3(8, 256), 256, 0, stream>>>(w3b, featb, b3, (float*)d_out);
}